// Round 14
// baseline (224.184 us; speedup 1.0000x reference)
//
#include <hip/hip_runtime.h>
#include <hip/hip_fp16.h>

#define N_NODES 100000
#define N_EDGES 1600000
#define IN_DIM 128
#define HID_DIM 64
#define OUT_DIM 64
#define NBKT 196    // node buckets of 512: ceil(100000/512)
#define BSH 9       // bucket shift
#define BMSK 511
#define NBLK 500    // edge-chunk blocks
#define CHUNK 3200  // 500*3200 = 1,600,000
#define MROW (NBKT * NBLK)   // 98,000
#define SLICE_STRIDE ((size_t)N_NODES * 8)   // halves per channel-slice

typedef _Float16 half8 __attribute__((ext_vector_type(8)));
typedef float f32x4 __attribute__((ext_vector_type(4)));

// ============ count (+ merged wfrag) ============
__global__ void count_kernel(const int* __restrict__ rows, const int* __restrict__ cols,
                             int* __restrict__ M,
                             const float* __restrict__ W1, const float* __restrict__ W2,
                             __half* __restrict__ F1, __half* __restrict__ F2) {
    __shared__ unsigned hc[NBKT], hr[NBKT];
    if (blockIdx.x >= NBLK) {
        int t = (blockIdx.x - NBLK) * 256 + threadIdx.x;
        if (t < 1024) {
            int lane = t & 63, fg = t >> 6;
            int col = (fg & 3) * 16 + (lane & 15);
            int kb = (fg >> 2) * 32 + (lane >> 4) * 8;
            __half v[8];
#pragma unroll
            for (int j = 0; j < 8; ++j) v[j] = __float2half(W1[(kb + j) * 64 + col]);
            *reinterpret_cast<uint4*>(F1 + (size_t)t * 8) = *reinterpret_cast<uint4*>(v);
        } else if (t < 1536) {
            int u = t - 1024;
            int lane = u & 63, fg = u >> 6;
            int col = (fg & 3) * 16 + (lane & 15);
            int kb = (fg >> 2) * 32 + (lane >> 4) * 8;
            __half v[8];
#pragma unroll
            for (int j = 0; j < 8; ++j) v[j] = __float2half(W2[(kb + j) * 64 + col]);
            *reinterpret_cast<uint4*>(F2 + (size_t)u * 8) = *reinterpret_cast<uint4*>(v);
        }
        return;
    }
    for (int i = threadIdx.x; i < NBKT; i += 256) { hc[i] = 0; hr[i] = 0; }
    __syncthreads();
    const int4* r4 = (const int4*)(rows + blockIdx.x * CHUNK);
    const int4* c4 = (const int4*)(cols + blockIdx.x * CHUNK);
    for (int i = threadIdx.x; i < CHUNK / 4; i += 256) {
        int4 r = r4[i], c = c4[i];
        atomicAdd(&hr[r.x >> BSH], 1u); atomicAdd(&hr[r.y >> BSH], 1u);
        atomicAdd(&hr[r.z >> BSH], 1u); atomicAdd(&hr[r.w >> BSH], 1u);
        atomicAdd(&hc[c.x >> BSH], 1u); atomicAdd(&hc[c.y >> BSH], 1u);
        atomicAdd(&hc[c.z >> BSH], 1u); atomicAdd(&hc[c.w >> BSH], 1u);
    }
    __syncthreads();
    for (int i = threadIdx.x; i < NBKT; i += 256) {
        M[i * NBLK + blockIdx.x] = (int)hc[i];
        M[MROW + i * NBLK + blockIdx.x] = (int)hr[i];
    }
}

// ============ exclusive scan (3 kernels) ============
__global__ void block_sum_kernel(const int* __restrict__ counts, int* __restrict__ partials, int n) {
    __shared__ int sh[256];
    int base = blockIdx.x * 1024;
    int s = 0;
    for (int i = threadIdx.x; i < 1024; i += 256) {
        int idx = base + i;
        s += (idx < n) ? counts[idx] : 0;
    }
    sh[threadIdx.x] = s;
    __syncthreads();
    for (int off = 128; off > 0; off >>= 1) {
        if (threadIdx.x < off) sh[threadIdx.x] += sh[threadIdx.x + off];
        __syncthreads();
    }
    if (threadIdx.x == 0) partials[blockIdx.x] = sh[0];
}

__global__ void scan_partials_kernel(int* __restrict__ p, int nb) {
    __shared__ int sh[256];
    int t = threadIdx.x;
    int v = (t < nb) ? p[t] : 0;
    sh[t] = v;
    __syncthreads();
    for (int off = 1; off < 256; off <<= 1) {
        int add = (t >= off) ? sh[t - off] : 0;
        __syncthreads();
        sh[t] += add;
        __syncthreads();
    }
    if (t < nb) p[t] = sh[t] - v;  // exclusive
}

__global__ void scan_final_kernel(const int* __restrict__ counts, const int* __restrict__ partials,
                                  int* __restrict__ offsets, int n) {
    __shared__ int sh[256];
    int t = threadIdx.x;
    int idx0 = blockIdx.x * 1024 + t * 4;
    int v[4];
    int s = 0;
#pragma unroll
    for (int j = 0; j < 4; ++j) {
        int id = idx0 + j;
        v[j] = (id < n) ? counts[id] : 0;
        s += v[j];
    }
    sh[t] = s;
    __syncthreads();
    for (int off = 1; off < 256; off <<= 1) {
        int add = (t >= off) ? sh[t - off] : 0;
        __syncthreads();
        sh[t] += add;
        __syncthreads();
    }
    int run = sh[t] - s + partials[blockIdx.x];
#pragma unroll
    for (int j = 0; j < 4; ++j) {
        int id = idx0 + j;
        if (id < n) offsets[id] = run;
        run += v[j];
    }
    if (idx0 <= n - 1 && n - 1 < idx0 + 4) offsets[n] = run;
}

// ============ scatter: block-local LDS counting sort, coalesced write-out ============
__global__ __launch_bounds__(256) void scatter_kernel(
        const int* __restrict__ rows, const int* __restrict__ cols,
        const float* __restrict__ w, const int* __restrict__ M, const int* __restrict__ Ms,
        unsigned long long* __restrict__ pkA, unsigned* __restrict__ pkR) {
    __shared__ unsigned long long pay[CHUNK];
    __shared__ unsigned char bkt[CHUNK];
    __shared__ unsigned scn[256];
    __shared__ unsigned base[NBKT], cur[NBKT], gbase[NBKT];
    const int blk = blockIdx.x, t = threadIdx.x;
    const int s = blk * CHUNK;
    const int4* r4 = (const int4*)(rows + s);
    const int4* c4 = (const int4*)(cols + s);
    const float4* w4 = (const float4*)(w + s);

    unsigned cnt = (t < NBKT) ? (unsigned)M[t * NBLK + blk] : 0;
    scn[t] = cnt;
    __syncthreads();
    for (int off = 1; off < 256; off <<= 1) {
        unsigned a = (t >= off) ? scn[t - off] : 0;
        __syncthreads();
        scn[t] += a;
        __syncthreads();
    }
    if (t < NBKT) {
        unsigned b0 = scn[t] - cnt;
        base[t] = b0; cur[t] = b0;
        gbase[t] = (unsigned)Ms[t * NBLK + blk];
    }
    __syncthreads();
#define PUTA(RV, CV, WV) { unsigned b = (unsigned)(CV) >> BSH; \
        unsigned p = atomicAdd(&cur[b], 1u); \
        pay[p] = ((unsigned long long)__float_as_uint(WV) << 32) | \
                 (unsigned)((((CV) & BMSK) << 17) | (RV)); \
        bkt[p] = (unsigned char)b; }
    for (int i = t; i < CHUNK / 4; i += 256) {
        int4 rr = r4[i]; int4 cc = c4[i]; float4 ww = w4[i];
        PUTA(rr.x, cc.x, ww.x); PUTA(rr.y, cc.y, ww.y);
        PUTA(rr.z, cc.z, ww.z); PUTA(rr.w, cc.w, ww.w);
    }
    __syncthreads();
    for (int i = t; i < CHUNK; i += 256) {
        unsigned b = bkt[i];
        pkA[gbase[b] + (i - base[b])] = pay[i];
    }
    __syncthreads();

    cnt = (t < NBKT) ? (unsigned)M[MROW + t * NBLK + blk] : 0;
    scn[t] = cnt;
    __syncthreads();
    for (int off = 1; off < 256; off <<= 1) {
        unsigned a = (t >= off) ? scn[t - off] : 0;
        __syncthreads();
        scn[t] += a;
        __syncthreads();
    }
    if (t < NBKT) {
        unsigned b0 = scn[t] - cnt;
        base[t] = b0; cur[t] = b0;
        gbase[t] = (unsigned)Ms[MROW + t * NBLK + blk] - (unsigned)N_EDGES;
    }
    __syncthreads();
    unsigned* pay32 = (unsigned*)pay;
#define PUTR(RV, WV) { unsigned b = (unsigned)(RV) >> BSH; \
        unsigned p = atomicAdd(&cur[b], 1u); \
        pay32[p] = ((unsigned)__half_as_ushort(__float2half(WV)) << 16) | (unsigned)((RV) & BMSK); \
        bkt[p] = (unsigned char)b; }
    for (int i = t; i < CHUNK / 4; i += 256) {
        int4 rr = r4[i]; float4 ww = w4[i];
        PUTR(rr.x, ww.x); PUTR(rr.y, ww.y); PUTR(rr.z, ww.z); PUTR(rr.w, ww.w);
    }
    __syncthreads();
    for (int i = t; i < CHUNK; i += 256) {
        unsigned b = bkt[i];
        pkR[gbase[b] + (i - base[b])] = pay32[i];
    }
}

// ============ merged fill (col region) + deg reduce (row region) ============
__global__ __launch_bounds__(256) void fill_deg_kernel(
        const unsigned long long* __restrict__ pkA, const unsigned* __restrict__ pkR,
        const int* __restrict__ Ms, int2* __restrict__ csr,
        int* __restrict__ offsets, float* __restrict__ dis) {
    __shared__ unsigned sh[768];
    const int t = threadIdx.x;
    if (blockIdx.x < NBKT) {
        unsigned* hist = sh;
        unsigned* pairs = sh + 512;
        const int b = blockIdx.x;
        hist[t] = 0; hist[t + 256] = 0;
        __syncthreads();
        const int s = Ms[b * NBLK];
        const int e = Ms[(b + 1) * NBLK];
        for (int i = s + t; i < e; i += 256) {
            unsigned lo = (unsigned)pkA[i];
            atomicAdd(&hist[(lo >> 17) & (unsigned)BMSK], 1u);
        }
        __syncthreads();
        unsigned h0 = hist[2 * t], h1 = hist[2 * t + 1];
        pairs[t] = h0 + h1;
        __syncthreads();
        for (int off = 1; off < 256; off <<= 1) {
            unsigned add = (t >= off) ? pairs[t - off] : 0;
            __syncthreads();
            pairs[t] += add;
            __syncthreads();
        }
        unsigned P = pairs[t] - (h0 + h1) + (unsigned)s;
        unsigned e0 = P, e1 = P + h0;
        int n0 = b * 512 + 2 * t;
        int n1 = n0 + 1;
        if (n0 <= N_NODES) offsets[n0] = (int)e0;
        if (n1 <= N_NODES) offsets[n1] = (int)e1;
        hist[2 * t] = e0; hist[2 * t + 1] = e1;
        __syncthreads();
        for (int i = s + t; i < e; i += 256) {
            unsigned long long p = pkA[i];
            unsigned lo = (unsigned)p;
            unsigned cl = (lo >> 17) & (unsigned)BMSK;
            int r = (int)(lo & 0x1FFFFu);
            unsigned pos = atomicAdd(&hist[cl], 1u);
            csr[pos] = make_int2(r, (int)(unsigned)(p >> 32));
        }
    } else {
        float* acc = (float*)sh;
        const int b = blockIdx.x - NBKT;
        acc[t] = 0.f; acc[t + 256] = 0.f;
        __syncthreads();
        const int s = Ms[MROW + b * NBLK] - N_EDGES;
        const int e = Ms[MROW + (b + 1) * NBLK] - N_EDGES;
        for (int i = s + t; i < e; i += 256) {
            unsigned u = pkR[i];
            float wv = __half2float(__ushort_as_half((unsigned short)(u >> 16)));
            atomicAdd(&acc[u & (unsigned)BMSK], wv);
        }
        __syncthreads();
#pragma unroll
        for (int k = 0; k < 2; ++k) {
            int node = b * 512 + t + k * 256;
            if (node < N_NODES) {
                float d = acc[t + k * 256];
                dis[node] = d > 0.f ? rsqrtf(fmaxf(d, 1e-12f)) : 0.f;
            }
        }
    }
}

// ============ GEMM1 (MFMA): h1 = dis * (x @ W1), SLICE-MAJOR fp16 out ============
__global__ __launch_bounds__(256) void gemm1_mfma(
        const float* __restrict__ x, const __half* __restrict__ F1,
        const float* __restrict__ dis, __half* __restrict__ h1) {
    const int wid = threadIdx.x >> 6, lane = threadIdx.x & 63;
    const int row0 = blockIdx.x * 64 + wid * 16;
    int arow = min(row0 + (lane & 15), N_NODES - 1);
    const int kb0 = (lane >> 4) * 8;
    const float* ap = x + (size_t)arow * 128 + kb0;

    f32x4 acc[4] = {};
#pragma unroll
    for (int c = 0; c < 4; ++c) {
        float4 a0 = *reinterpret_cast<const float4*>(ap + c * 32);
        float4 a1 = *reinterpret_cast<const float4*>(ap + c * 32 + 4);
        half8 af;
        af[0] = (_Float16)a0.x; af[1] = (_Float16)a0.y; af[2] = (_Float16)a0.z; af[3] = (_Float16)a0.w;
        af[4] = (_Float16)a1.x; af[5] = (_Float16)a1.y; af[6] = (_Float16)a1.z; af[7] = (_Float16)a1.w;
#pragma unroll
        for (int ct = 0; ct < 4; ++ct) {
            half8 bf = *reinterpret_cast<const half8*>(F1 + ((size_t)(c * 4 + ct) * 64 + lane) * 8);
            acc[ct] = __builtin_amdgcn_mfma_f32_16x16x32_f16(af, bf, acc[ct], 0, 0, 0);
        }
    }
    const int prow = row0 + ((lane >> 4) << 2);
    const int col = lane & 15;
#pragma unroll
    for (int r = 0; r < 4; ++r) {
        int rr = prow + r;
        if (rr < N_NODES) {
            float dv = dis[rr];
#pragma unroll
            for (int ct = 0; ct < 4; ++ct) {
                int ch = ct * 16 + col;
                h1[(size_t)(ch >> 3) * SLICE_STRIDE + (size_t)rr * 8 + (ch & 7)] =
                    __float2half(acc[ct][r] * dv);
            }
        }
    }
}

// ============ GEMM2 (MFMA): out = g @ W2 + b2 (g is slice-major), fp32 out ============
__global__ __launch_bounds__(256) void gemm2_mfma(
        const __half* __restrict__ g, const __half* __restrict__ F2,
        const float* __restrict__ b2, float* __restrict__ out) {
    const int wid = threadIdx.x >> 6, lane = threadIdx.x & 63;
    const int row0 = blockIdx.x * 64 + wid * 16;
    int arow = min(row0 + (lane & 15), N_NODES - 1);
    const int kb0 = (lane >> 4) * 8;

    f32x4 acc[4] = {};
#pragma unroll
    for (int c = 0; c < 2; ++c) {
        int sl = (kb0 + c * 32) >> 3;   // slice of this k-octet
        half8 af = *reinterpret_cast<const half8*>(g + (size_t)sl * SLICE_STRIDE + (size_t)arow * 8);
#pragma unroll
        for (int ct = 0; ct < 4; ++ct) {
            half8 bf = *reinterpret_cast<const half8*>(F2 + ((size_t)(c * 4 + ct) * 64 + lane) * 8);
            acc[ct] = __builtin_amdgcn_mfma_f32_16x16x32_f16(af, bf, acc[ct], 0, 0, 0);
        }
    }
    const int prow = row0 + ((lane >> 4) << 2);
    const int col = lane & 15;
#pragma unroll
    for (int ct = 0; ct < 4; ++ct) {
        float bb = b2[ct * 16 + col];
#pragma unroll
        for (int r = 0; r < 4; ++r) {
            int rr = prow + r;
            if (rr < N_NODES) out[(size_t)rr * 64 + ct * 16 + col] = acc[ct][r] + bb;
        }
    }
}

// ============ gather: channel-sliced, XCD-affine (slice = blockIdx & 7) ============
// Block = 512 thr = 8 waves x (8 nodes x 8 edge-slots). Slice s touches only the
// contiguous 1.6MB stripe h[s] -> L2-resident on its XCD (round-robin dispatch).
// Per-lane loop bounds: exec mask handles degree variance, zero padded loads.
__device__ __forceinline__ void fma8(float* a, uint4 u, float nv) {
    float2 f;
    f = __half22float2(__builtin_bit_cast(__half2, u.x)); a[0] = fmaf(f.x, nv, a[0]); a[1] = fmaf(f.y, nv, a[1]);
    f = __half22float2(__builtin_bit_cast(__half2, u.y)); a[2] = fmaf(f.x, nv, a[2]); a[3] = fmaf(f.y, nv, a[3]);
    f = __half22float2(__builtin_bit_cast(__half2, u.z)); a[4] = fmaf(f.x, nv, a[4]); a[5] = fmaf(f.y, nv, a[5]);
    f = __half22float2(__builtin_bit_cast(__half2, u.w)); a[6] = fmaf(f.x, nv, a[6]); a[7] = fmaf(f.y, nv, a[7]);
}

template <int BIAS_RELU>
__global__ __launch_bounds__(512) void gather_slice_kernel(
        const __half* __restrict__ hS, const int2* __restrict__ csr,
        const int* __restrict__ offsets, const float* __restrict__ bias,
        const float* __restrict__ dis, __half* __restrict__ outS) {
    const int s = blockIdx.x & 7;          // slice == XCD under round-robin dispatch
    const int chunk = blockIdx.x >> 3;
    const int lane = threadIdx.x & 63;
    const int eslot = lane & 7;
    const int node = chunk * 64 + (threadIdx.x >> 6) * 8 + (lane >> 3);
    const __half* hp = hS + (size_t)s * SLICE_STRIDE;

    int sn = 0, en = 0;
    if (node < N_NODES) { sn = offsets[node]; en = offsets[node + 1]; }

    float a[8] = {};
    for (int j = sn + eslot; j < en; j += 8) {
        int2 p = csr[j];
        uint4 u = *reinterpret_cast<const uint4*>(hp + (size_t)p.x * 8);
        fma8(a, u, __int_as_float(p.y));
    }
#pragma unroll
    for (int m = 1; m <= 4; m <<= 1)
#pragma unroll
        for (int k = 0; k < 8; ++k) a[k] += __shfl_xor(a[k], m);

    if (eslot == 0 && node < N_NODES) {
        float dv = dis[node];
        if (BIAS_RELU) {
            const float4 b0 = *reinterpret_cast<const float4*>(bias + s * 8);
            const float4 b1 = *reinterpret_cast<const float4*>(bias + s * 8 + 4);
            a[0] = fmaxf(fmaf(a[0], dv, b0.x), 0.f) * dv; a[1] = fmaxf(fmaf(a[1], dv, b0.y), 0.f) * dv;
            a[2] = fmaxf(fmaf(a[2], dv, b0.z), 0.f) * dv; a[3] = fmaxf(fmaf(a[3], dv, b0.w), 0.f) * dv;
            a[4] = fmaxf(fmaf(a[4], dv, b1.x), 0.f) * dv; a[5] = fmaxf(fmaf(a[5], dv, b1.y), 0.f) * dv;
            a[6] = fmaxf(fmaf(a[6], dv, b1.z), 0.f) * dv; a[7] = fmaxf(fmaf(a[7], dv, b1.w), 0.f) * dv;
        } else {
#pragma unroll
            for (int k = 0; k < 8; ++k) a[k] *= dv;
        }
        __half2 o0 = __float22half2_rn(make_float2(a[0], a[1]));
        __half2 o1 = __float22half2_rn(make_float2(a[2], a[3]));
        __half2 o2 = __float22half2_rn(make_float2(a[4], a[5]));
        __half2 o3 = __float22half2_rn(make_float2(a[6], a[7]));
        uint4 u = make_uint4(__builtin_bit_cast(unsigned, o0), __builtin_bit_cast(unsigned, o1),
                             __builtin_bit_cast(unsigned, o2), __builtin_bit_cast(unsigned, o3));
        *reinterpret_cast<uint4*>(outS + (size_t)s * SLICE_STRIDE + (size_t)node * 8) = u;
    }
}

extern "C" void kernel_launch(void* const* d_in, const int* in_sizes, int n_in,
                              void* d_out, int out_size, void* d_ws, size_t ws_size,
                              hipStream_t stream) {
    const float* x  = (const float*)d_in[0];
    const int*   ei = (const int*)d_in[1];
    const float* ew = (const float*)d_in[2];
    const float* W1 = (const float*)d_in[3];
    const float* b1 = (const float*)d_in[4];
    const float* W2 = (const float*)d_in[5];
    const float* b2 = (const float*)d_in[6];
    float* out = (float*)d_out;
    char*  ws  = (char*)d_ws;

    const int* rows = ei;
    const int* cols = ei + N_EDGES;

    // ---- workspace (byte offsets) ----
    int2*     csr      = (int2*)(ws + 0);                      // 12,800,000
    unsigned long long* pkA = (unsigned long long*)(ws + 12800000);  // [dies at fill]
    unsigned* pkR      = (unsigned*)(ws + 25600000);           // [dies at deg]
    __half*   h1       = (__half*)(ws + 12800000);             // slice-major fp16, over pkA
    __half*   g        = (__half*)(ws + 12800000);             // over h1 (gather2 out)
    __half*   t        = (__half*)(ws + 25600000);             // over pkR (gather1 out)
    int*      M        = (int*)(ws + 38400000);                // 784,000
    int*      Ms       = (int*)(ws + 39184000);                // 784,004
    int*      partials = (int*)(ws + 39968016);                // 768
    int*      offsets  = (int*)(ws + 39968784);                // 400,004
    float*    dis      = (float*)(ws + 40368800);              // 400,000
    __half*   F1       = (__half*)(ws + 40768800);             // 16,384
    __half*   F2       = (__half*)(ws + 40785184);             // 8,192

    const int TPB = 256;
    const int n2  = 2 * MROW;                    // 196,000
    const int nSB2 = (n2 + 1023) / 1024;         // 192
    const int nChunks = (N_NODES + 63) / 64;     // 1563

    // 1) histograms (+ merged W-fragment pack)
    count_kernel<<<NBLK + 6, TPB, 0, stream>>>(rows, cols, M, W1, W2, F1, F2);

    // 2) one scan chain
    block_sum_kernel<<<nSB2, 256, 0, stream>>>(M, partials, n2);
    scan_partials_kernel<<<1, 256, 0, stream>>>(partials, nSB2);
    scan_final_kernel<<<nSB2, 256, 0, stream>>>(M, partials, Ms, n2);

    // 3) LDS-sorted scatter
    scatter_kernel<<<NBLK, TPB, 0, stream>>>(rows, cols, ew, M, Ms, pkA, pkR);

    // 4) fill ∥ deg
    fill_deg_kernel<<<2 * NBKT, TPB, 0, stream>>>(pkA, pkR, Ms, csr, offsets, dis);

    // 5) h1 = dis * (x @ W1), slice-major (over dead pkA)
    gemm1_mfma<<<(N_NODES + 63) / 64, TPB, 0, stream>>>(x, F1, dis, h1);

    // 6) t = dis*relu(dis*gather(h1) + b1), sliced + XCD-affine (over dead pkR)
    gather_slice_kernel<1><<<nChunks * 8, 512, 0, stream>>>(h1, csr, offsets, b1, dis, t);

    // 7) g = dis*gather(t) (over dead h1)
    gather_slice_kernel<0><<<nChunks * 8, 512, 0, stream>>>(t, csr, offsets, b1, dis, g);

    // 8) out = g @ W2 + b2
    gemm2_mfma<<<(N_NODES + 63) / 64, TPB, 0, stream>>>(g, F2, b2, out);
}

// Round 15
// 167.045 us; speedup vs baseline: 1.3421x; 1.3421x over previous
//
#include <hip/hip_runtime.h>
#include <hip/hip_fp16.h>

#define N_NODES 100000
#define N_EDGES 1600000
#define IN_DIM 128
#define HID_DIM 64
#define OUT_DIM 64
#define NBKT 196    // node buckets of 512: ceil(100000/512)
#define BSH 9       // bucket shift
#define BMSK 511
#define NBLK 500    // edge-chunk blocks
#define CHUNK 3200  // 500*3200 = 1,600,000
#define MROW (NBKT * NBLK)   // 98,000

typedef _Float16 half8 __attribute__((ext_vector_type(8)));
typedef float f32x4 __attribute__((ext_vector_type(4)));
typedef unsigned uint4v __attribute__((ext_vector_type(4)));
typedef unsigned long long u64;

__device__ __forceinline__ int2 ldnt_i2(const int2* p) {
    u64 v = __builtin_nontemporal_load((const u64*)p);
    return make_int2((int)(unsigned)v, (int)(v >> 32));
}
__device__ __forceinline__ void stnt_u4(void* p, uint4 v) {
    uint4v t = {v.x, v.y, v.z, v.w};
    __builtin_nontemporal_store(t, (uint4v*)p);
}

// ============ count (+ merged wfrag) ============
__global__ void count_kernel(const int* __restrict__ rows, const int* __restrict__ cols,
                             int* __restrict__ M,
                             const float* __restrict__ W1, const float* __restrict__ W2,
                             __half* __restrict__ F1, __half* __restrict__ F2) {
    __shared__ unsigned hc[NBKT], hr[NBKT];
    if (blockIdx.x >= NBLK) {
        int t = (blockIdx.x - NBLK) * 256 + threadIdx.x;
        if (t < 1024) {
            int lane = t & 63, fg = t >> 6;
            int col = (fg & 3) * 16 + (lane & 15);
            int kb = (fg >> 2) * 32 + (lane >> 4) * 8;
            __half v[8];
#pragma unroll
            for (int j = 0; j < 8; ++j) v[j] = __float2half(W1[(kb + j) * 64 + col]);
            *reinterpret_cast<uint4*>(F1 + (size_t)t * 8) = *reinterpret_cast<uint4*>(v);
        } else if (t < 1536) {
            int u = t - 1024;
            int lane = u & 63, fg = u >> 6;
            int col = (fg & 3) * 16 + (lane & 15);
            int kb = (fg >> 2) * 32 + (lane >> 4) * 8;
            __half v[8];
#pragma unroll
            for (int j = 0; j < 8; ++j) v[j] = __float2half(W2[(kb + j) * 64 + col]);
            *reinterpret_cast<uint4*>(F2 + (size_t)u * 8) = *reinterpret_cast<uint4*>(v);
        }
        return;
    }
    for (int i = threadIdx.x; i < NBKT; i += 256) { hc[i] = 0; hr[i] = 0; }
    __syncthreads();
    const int4* r4 = (const int4*)(rows + blockIdx.x * CHUNK);
    const int4* c4 = (const int4*)(cols + blockIdx.x * CHUNK);
    for (int i = threadIdx.x; i < CHUNK / 4; i += 256) {
        int4 r = r4[i], c = c4[i];
        atomicAdd(&hr[r.x >> BSH], 1u); atomicAdd(&hr[r.y >> BSH], 1u);
        atomicAdd(&hr[r.z >> BSH], 1u); atomicAdd(&hr[r.w >> BSH], 1u);
        atomicAdd(&hc[c.x >> BSH], 1u); atomicAdd(&hc[c.y >> BSH], 1u);
        atomicAdd(&hc[c.z >> BSH], 1u); atomicAdd(&hc[c.w >> BSH], 1u);
    }
    __syncthreads();
    for (int i = threadIdx.x; i < NBKT; i += 256) {
        M[i * NBLK + blockIdx.x] = (int)hc[i];
        M[MROW + i * NBLK + blockIdx.x] = (int)hr[i];
    }
}

// ============ exclusive scan (3 kernels) ============
__global__ void block_sum_kernel(const int* __restrict__ counts, int* __restrict__ partials, int n) {
    __shared__ int sh[256];
    int base = blockIdx.x * 1024;
    int s = 0;
    for (int i = threadIdx.x; i < 1024; i += 256) {
        int idx = base + i;
        s += (idx < n) ? counts[idx] : 0;
    }
    sh[threadIdx.x] = s;
    __syncthreads();
    for (int off = 128; off > 0; off >>= 1) {
        if (threadIdx.x < off) sh[threadIdx.x] += sh[threadIdx.x + off];
        __syncthreads();
    }
    if (threadIdx.x == 0) partials[blockIdx.x] = sh[0];
}

__global__ void scan_partials_kernel(int* __restrict__ p, int nb) {
    __shared__ int sh[256];
    int t = threadIdx.x;
    int v = (t < nb) ? p[t] : 0;
    sh[t] = v;
    __syncthreads();
    for (int off = 1; off < 256; off <<= 1) {
        int add = (t >= off) ? sh[t - off] : 0;
        __syncthreads();
        sh[t] += add;
        __syncthreads();
    }
    if (t < nb) p[t] = sh[t] - v;  // exclusive
}

__global__ void scan_final_kernel(const int* __restrict__ counts, const int* __restrict__ partials,
                                  int* __restrict__ offsets, int n) {
    __shared__ int sh[256];
    int t = threadIdx.x;
    int idx0 = blockIdx.x * 1024 + t * 4;
    int v[4];
    int s = 0;
#pragma unroll
    for (int j = 0; j < 4; ++j) {
        int id = idx0 + j;
        v[j] = (id < n) ? counts[id] : 0;
        s += v[j];
    }
    sh[t] = s;
    __syncthreads();
    for (int off = 1; off < 256; off <<= 1) {
        int add = (t >= off) ? sh[t - off] : 0;
        __syncthreads();
        sh[t] += add;
        __syncthreads();
    }
    int run = sh[t] - s + partials[blockIdx.x];
#pragma unroll
    for (int j = 0; j < 4; ++j) {
        int id = idx0 + j;
        if (id < n) offsets[id] = run;
        run += v[j];
    }
    if (idx0 <= n - 1 && n - 1 < idx0 + 4) offsets[n] = run;
}

// ============ scatter: block-local LDS counting sort, coalesced write-out ============
__global__ __launch_bounds__(256) void scatter_kernel(
        const int* __restrict__ rows, const int* __restrict__ cols,
        const float* __restrict__ w, const int* __restrict__ M, const int* __restrict__ Ms,
        unsigned long long* __restrict__ pkA, unsigned* __restrict__ pkR) {
    __shared__ unsigned long long pay[CHUNK];
    __shared__ unsigned char bkt[CHUNK];
    __shared__ unsigned scn[256];
    __shared__ unsigned base[NBKT], cur[NBKT], gbase[NBKT];
    const int blk = blockIdx.x, t = threadIdx.x;
    const int s = blk * CHUNK;
    const int4* r4 = (const int4*)(rows + s);
    const int4* c4 = (const int4*)(cols + s);
    const float4* w4 = (const float4*)(w + s);

    unsigned cnt = (t < NBKT) ? (unsigned)M[t * NBLK + blk] : 0;
    scn[t] = cnt;
    __syncthreads();
    for (int off = 1; off < 256; off <<= 1) {
        unsigned a = (t >= off) ? scn[t - off] : 0;
        __syncthreads();
        scn[t] += a;
        __syncthreads();
    }
    if (t < NBKT) {
        unsigned b0 = scn[t] - cnt;
        base[t] = b0; cur[t] = b0;
        gbase[t] = (unsigned)Ms[t * NBLK + blk];
    }
    __syncthreads();
#define PUTA(RV, CV, WV) { unsigned b = (unsigned)(CV) >> BSH; \
        unsigned p = atomicAdd(&cur[b], 1u); \
        pay[p] = ((unsigned long long)__float_as_uint(WV) << 32) | \
                 (unsigned)((((CV) & BMSK) << 17) | (RV)); \
        bkt[p] = (unsigned char)b; }
    for (int i = t; i < CHUNK / 4; i += 256) {
        int4 rr = r4[i]; int4 cc = c4[i]; float4 ww = w4[i];
        PUTA(rr.x, cc.x, ww.x); PUTA(rr.y, cc.y, ww.y);
        PUTA(rr.z, cc.z, ww.z); PUTA(rr.w, cc.w, ww.w);
    }
    __syncthreads();
    for (int i = t; i < CHUNK; i += 256) {
        unsigned b = bkt[i];
        pkA[gbase[b] + (i - base[b])] = pay[i];
    }
    __syncthreads();

    cnt = (t < NBKT) ? (unsigned)M[MROW + t * NBLK + blk] : 0;
    scn[t] = cnt;
    __syncthreads();
    for (int off = 1; off < 256; off <<= 1) {
        unsigned a = (t >= off) ? scn[t - off] : 0;
        __syncthreads();
        scn[t] += a;
        __syncthreads();
    }
    if (t < NBKT) {
        unsigned b0 = scn[t] - cnt;
        base[t] = b0; cur[t] = b0;
        gbase[t] = (unsigned)Ms[MROW + t * NBLK + blk] - (unsigned)N_EDGES;
    }
    __syncthreads();
    unsigned* pay32 = (unsigned*)pay;
#define PUTR(RV, WV) { unsigned b = (unsigned)(RV) >> BSH; \
        unsigned p = atomicAdd(&cur[b], 1u); \
        pay32[p] = ((unsigned)__half_as_ushort(__float2half(WV)) << 16) | (unsigned)((RV) & BMSK); \
        bkt[p] = (unsigned char)b; }
    for (int i = t; i < CHUNK / 4; i += 256) {
        int4 rr = r4[i]; float4 ww = w4[i];
        PUTR(rr.x, ww.x); PUTR(rr.y, ww.y); PUTR(rr.z, ww.z); PUTR(rr.w, ww.w);
    }
    __syncthreads();
    for (int i = t; i < CHUNK; i += 256) {
        unsigned b = bkt[i];
        pkR[gbase[b] + (i - base[b])] = pay32[i];
    }
}

// ============ merged fill (col region) + deg reduce (row region) ============
__global__ __launch_bounds__(256) void fill_deg_kernel(
        const unsigned long long* __restrict__ pkA, const unsigned* __restrict__ pkR,
        const int* __restrict__ Ms, int2* __restrict__ csr,
        int* __restrict__ offsets, float* __restrict__ dis) {
    __shared__ unsigned sh[768];
    const int t = threadIdx.x;
    if (blockIdx.x < NBKT) {
        unsigned* hist = sh;
        unsigned* pairs = sh + 512;
        const int b = blockIdx.x;
        hist[t] = 0; hist[t + 256] = 0;
        __syncthreads();
        const int s = Ms[b * NBLK];
        const int e = Ms[(b + 1) * NBLK];
        for (int i = s + t; i < e; i += 256) {
            unsigned lo = (unsigned)pkA[i];
            atomicAdd(&hist[(lo >> 17) & (unsigned)BMSK], 1u);
        }
        __syncthreads();
        unsigned h0 = hist[2 * t], h1 = hist[2 * t + 1];
        pairs[t] = h0 + h1;
        __syncthreads();
        for (int off = 1; off < 256; off <<= 1) {
            unsigned add = (t >= off) ? pairs[t - off] : 0;
            __syncthreads();
            pairs[t] += add;
            __syncthreads();
        }
        unsigned P = pairs[t] - (h0 + h1) + (unsigned)s;
        unsigned e0 = P, e1 = P + h0;
        int n0 = b * 512 + 2 * t;
        int n1 = n0 + 1;
        if (n0 <= N_NODES) offsets[n0] = (int)e0;
        if (n1 <= N_NODES) offsets[n1] = (int)e1;
        hist[2 * t] = e0; hist[2 * t + 1] = e1;
        __syncthreads();
        for (int i = s + t; i < e; i += 256) {
            unsigned long long p = pkA[i];
            unsigned lo = (unsigned)p;
            unsigned cl = (lo >> 17) & (unsigned)BMSK;
            int r = (int)(lo & 0x1FFFFu);
            unsigned pos = atomicAdd(&hist[cl], 1u);
            csr[pos] = make_int2(r, (int)(unsigned)(p >> 32));
        }
    } else {
        float* acc = (float*)sh;
        const int b = blockIdx.x - NBKT;
        acc[t] = 0.f; acc[t + 256] = 0.f;
        __syncthreads();
        const int s = Ms[MROW + b * NBLK] - N_EDGES;
        const int e = Ms[MROW + (b + 1) * NBLK] - N_EDGES;
        for (int i = s + t; i < e; i += 256) {
            unsigned u = pkR[i];
            float wv = __half2float(__ushort_as_half((unsigned short)(u >> 16)));
            atomicAdd(&acc[u & (unsigned)BMSK], wv);
        }
        __syncthreads();
#pragma unroll
        for (int k = 0; k < 2; ++k) {
            int node = b * 512 + t + k * 256;
            if (node < N_NODES) {
                float d = acc[t + k * 256];
                dis[node] = d > 0.f ? rsqrtf(fmaxf(d, 1e-12f)) : 0.f;
            }
        }
    }
}

// ============ GEMM1 (MFMA): h1[r] = dis[r] * (x @ W1)[r], row-major fp16 out ============
__global__ __launch_bounds__(256) void gemm1_mfma(
        const float* __restrict__ x, const __half* __restrict__ F1,
        const float* __restrict__ dis, __half* __restrict__ h1) {
    const int wid = threadIdx.x >> 6, lane = threadIdx.x & 63;
    const int row0 = blockIdx.x * 64 + wid * 16;
    int arow = min(row0 + (lane & 15), N_NODES - 1);
    const int kb0 = (lane >> 4) * 8;
    const float* ap = x + (size_t)arow * 128 + kb0;

    f32x4 acc[4] = {};
#pragma unroll
    for (int c = 0; c < 4; ++c) {
        float4 a0 = *reinterpret_cast<const float4*>(ap + c * 32);
        float4 a1 = *reinterpret_cast<const float4*>(ap + c * 32 + 4);
        half8 af;
        af[0] = (_Float16)a0.x; af[1] = (_Float16)a0.y; af[2] = (_Float16)a0.z; af[3] = (_Float16)a0.w;
        af[4] = (_Float16)a1.x; af[5] = (_Float16)a1.y; af[6] = (_Float16)a1.z; af[7] = (_Float16)a1.w;
#pragma unroll
        for (int ct = 0; ct < 4; ++ct) {
            half8 bf = *reinterpret_cast<const half8*>(F1 + ((size_t)(c * 4 + ct) * 64 + lane) * 8);
            acc[ct] = __builtin_amdgcn_mfma_f32_16x16x32_f16(af, bf, acc[ct], 0, 0, 0);
        }
    }
    const int prow = row0 + ((lane >> 4) << 2);
    const int col = lane & 15;
#pragma unroll
    for (int r = 0; r < 4; ++r) {
        int rr = prow + r;
        if (rr < N_NODES) {
            float dv = dis[rr];
#pragma unroll
            for (int ct = 0; ct < 4; ++ct)
                h1[(size_t)rr * 64 + ct * 16 + col] = __float2half(acc[ct][r] * dv);
        }
    }
}

// ============ gather core: 2 nodes/wave, 32 edges in flight ============
__device__ __forceinline__ void fma8(float* a, uint4 u, float nv) {
    float2 f;
    f = __half22float2(__builtin_bit_cast(__half2, u.x)); a[0] = fmaf(f.x, nv, a[0]); a[1] = fmaf(f.y, nv, a[1]);
    f = __half22float2(__builtin_bit_cast(__half2, u.y)); a[2] = fmaf(f.x, nv, a[2]); a[3] = fmaf(f.y, nv, a[3]);
    f = __half22float2(__builtin_bit_cast(__half2, u.z)); a[4] = fmaf(f.x, nv, a[4]); a[5] = fmaf(f.y, nv, a[5]);
    f = __half22float2(__builtin_bit_cast(__half2, u.w)); a[6] = fmaf(f.x, nv, a[6]); a[7] = fmaf(f.y, nv, a[7]);
}

// gather body: accumulates xa (node n0) and ya (node n1), full 8-lane-group reduce.
__device__ __forceinline__ void gather_pair(
        const __half* __restrict__ h, const int2* __restrict__ csr,
        const int* __restrict__ offsets, int n0, int n1, int q, int g,
        float* xa, float* ya) {
    const int s0 = offsets[n0], e0 = offsets[n0 + 1];
    const int s1 = offsets[n1], e1 = offsets[n1 + 1];
    const int cl0 = max(e0 - 1, s0);
    const int cl1 = max(e1 - 1, s1);
    const int L = max(e0 - s0, e1 - s1);
    for (int j = 0; j < L; j += 16) {
        int iA0 = s0 + j + g,     iB0 = s0 + j + 8 + g;
        int iA1 = s1 + j + g,     iB1 = s1 + j + 8 + g;
        int2 pA0 = ldnt_i2(&csr[min(iA0, cl0)]);
        int2 pB0 = ldnt_i2(&csr[min(iB0, cl0)]);
        int2 pA1 = ldnt_i2(&csr[min(iA1, cl1)]);
        int2 pB1 = ldnt_i2(&csr[min(iB1, cl1)]);
        uint4 uA0 = *reinterpret_cast<const uint4*>(h + ((size_t)pA0.x << 6) + (q << 3));
        uint4 uB0 = *reinterpret_cast<const uint4*>(h + ((size_t)pB0.x << 6) + (q << 3));
        uint4 uA1 = *reinterpret_cast<const uint4*>(h + ((size_t)pA1.x << 6) + (q << 3));
        uint4 uB1 = *reinterpret_cast<const uint4*>(h + ((size_t)pB1.x << 6) + (q << 3));
        float nA0 = (iA0 < e0) ? __int_as_float(pA0.y) : 0.f;
        float nB0 = (iB0 < e0) ? __int_as_float(pB0.y) : 0.f;
        float nA1 = (iA1 < e1) ? __int_as_float(pA1.y) : 0.f;
        float nB1 = (iB1 < e1) ? __int_as_float(pB1.y) : 0.f;
        fma8(xa, uA0, nA0); fma8(xa, uB0, nB0);
        fma8(ya, uA1, nA1); fma8(ya, uB1, nB1);
    }
#pragma unroll
    for (int m = 8; m <= 32; m <<= 1) {
#pragma unroll
        for (int k = 0; k < 8; ++k) {
            xa[k] += __shfl_xor(xa[k], m);
            ya[k] += __shfl_xor(ya[k], m);
        }
    }
}

// ============ gather1: t = dis*relu(dis*gather(h1) + b1), fp16 out (nt store) ============
__global__ __launch_bounds__(512) void gather1_kernel(
        const __half* __restrict__ h, const int2* __restrict__ csr,
        const int* __restrict__ offsets, const float* __restrict__ bias,
        const float* __restrict__ dis, __half* __restrict__ outh) {
    const int wid = threadIdx.x >> 6;
    const int n0 = blockIdx.x * 16 + wid * 2;
    const int n1 = n0 + 1;
    const int lane = threadIdx.x & 63;
    const int q = lane & 7;
    const int g = lane >> 3;

    float xa[8] = {}, ya[8] = {};
    gather_pair(h, csr, offsets, n0, n1, q, g, xa, ya);

    if (g <= 1) {
        float* a = (g == 0) ? xa : ya;
        int node = (g == 0) ? n0 : n1;
        float dv = dis[node];
        const float4 b0 = *reinterpret_cast<const float4*>(bias + (q << 3));
        const float4 b1 = *reinterpret_cast<const float4*>(bias + (q << 3) + 4);
        a[0] = fmaxf(fmaf(a[0], dv, b0.x), 0.f) * dv; a[1] = fmaxf(fmaf(a[1], dv, b0.y), 0.f) * dv;
        a[2] = fmaxf(fmaf(a[2], dv, b0.z), 0.f) * dv; a[3] = fmaxf(fmaf(a[3], dv, b0.w), 0.f) * dv;
        a[4] = fmaxf(fmaf(a[4], dv, b1.x), 0.f) * dv; a[5] = fmaxf(fmaf(a[5], dv, b1.y), 0.f) * dv;
        a[6] = fmaxf(fmaf(a[6], dv, b1.z), 0.f) * dv; a[7] = fmaxf(fmaf(a[7], dv, b1.w), 0.f) * dv;
        __half2 o0 = __float22half2_rn(make_float2(a[0], a[1]));
        __half2 o1 = __float22half2_rn(make_float2(a[2], a[3]));
        __half2 o2 = __float22half2_rn(make_float2(a[4], a[5]));
        __half2 o3 = __float22half2_rn(make_float2(a[6], a[7]));
        uint4 u = make_uint4(__builtin_bit_cast(unsigned, o0), __builtin_bit_cast(unsigned, o1),
                             __builtin_bit_cast(unsigned, o2), __builtin_bit_cast(unsigned, o3));
        stnt_u4(outh + ((size_t)node << 6) + (q << 3), u);
    }
}

// ============ gather2 + fused GEMM2: out = (dis*gather(t)) @ W2 + b2, fp32 out ============
// 8 waves x 2 nodes = 16 node-rows -> LDS [16][72] fp16 (padded, 2-way-free banks),
// then waves 0..3 each compute one 16-col tile via 2x MFMA 16x16x32 against F2.
__global__ __launch_bounds__(512) void gather2_gemm2_kernel(
        const __half* __restrict__ h, const int2* __restrict__ csr,
        const int* __restrict__ offsets, const float* __restrict__ dis,
        const __half* __restrict__ F2, const float* __restrict__ b2,
        float* __restrict__ out) {
    __shared__ __half rows[16][72];
    const int wid = threadIdx.x >> 6;
    const int n0 = blockIdx.x * 16 + wid * 2;
    const int n1 = n0 + 1;
    const int lane = threadIdx.x & 63;
    const int q = lane & 7;
    const int g = lane >> 3;

    float xa[8] = {}, ya[8] = {};
    gather_pair(h, csr, offsets, n0, n1, q, g, xa, ya);

    if (g <= 1) {
        float* a = (g == 0) ? xa : ya;
        int node = (g == 0) ? n0 : n1;
        float dv = dis[node];
#pragma unroll
        for (int k = 0; k < 8; ++k) a[k] *= dv;
        __half2 o0 = __float22half2_rn(make_float2(a[0], a[1]));
        __half2 o1 = __float22half2_rn(make_float2(a[2], a[3]));
        __half2 o2 = __float22half2_rn(make_float2(a[4], a[5]));
        __half2 o3 = __float22half2_rn(make_float2(a[6], a[7]));
        uint4 u = make_uint4(__builtin_bit_cast(unsigned, o0), __builtin_bit_cast(unsigned, o1),
                             __builtin_bit_cast(unsigned, o2), __builtin_bit_cast(unsigned, o3));
        *reinterpret_cast<uint4*>(&rows[wid * 2 + g][q << 3]) = u;
    }
    __syncthreads();

    if (wid < 4) {     // wave wid computes col-tile ct = wid over 16 rows, K = 64
        const int arow = lane & 15;
        const int kb0 = (lane >> 4) * 8;
        f32x4 acc = {};
#pragma unroll
        for (int c = 0; c < 2; ++c) {
            half8 af = *reinterpret_cast<const half8*>(&rows[arow][c * 32 + kb0]);
            half8 bf = *reinterpret_cast<const half8*>(F2 + ((size_t)(c * 4 + wid) * 64 + lane) * 8);
            acc = __builtin_amdgcn_mfma_f32_16x16x32_f16(af, bf, acc, 0, 0, 0);
        }
        const int col = lane & 15;
        const int prow = blockIdx.x * 16 + ((lane >> 4) << 2);
        float bb = b2[wid * 16 + col];
#pragma unroll
        for (int r = 0; r < 4; ++r)
            out[(size_t)(prow + r) * 64 + wid * 16 + col] = acc[r] + bb;
    }
}

extern "C" void kernel_launch(void* const* d_in, const int* in_sizes, int n_in,
                              void* d_out, int out_size, void* d_ws, size_t ws_size,
                              hipStream_t stream) {
    const float* x  = (const float*)d_in[0];
    const int*   ei = (const int*)d_in[1];
    const float* ew = (const float*)d_in[2];
    const float* W1 = (const float*)d_in[3];
    const float* b1 = (const float*)d_in[4];
    const float* W2 = (const float*)d_in[5];
    const float* b2 = (const float*)d_in[6];
    float* out = (float*)d_out;
    char*  ws  = (char*)d_ws;

    const int* rows = ei;
    const int* cols = ei + N_EDGES;

    // ---- workspace (byte offsets) ----
    int2*     csr      = (int2*)(ws + 0);                      // 12,800,000
    unsigned long long* pkA = (unsigned long long*)(ws + 12800000);  // [dies at fill]
    unsigned* pkR      = (unsigned*)(ws + 25600000);           // [dies at deg]
    __half*   h1       = (__half*)(ws + 12800000);             // fp16, over pkA
    __half*   t        = (__half*)(ws + 25600000);             // fp16, over pkR (gather1 out)
    int*      M        = (int*)(ws + 38400000);                // 784,000
    int*      Ms       = (int*)(ws + 39184000);                // 784,004
    int*      partials = (int*)(ws + 39968016);                // 768
    int*      offsets  = (int*)(ws + 39968784);                // 400,004
    float*    dis      = (float*)(ws + 40368800);              // 400,000
    __half*   F1       = (__half*)(ws + 40768800);             // 16,384
    __half*   F2       = (__half*)(ws + 40785184);             // 8,192

    const int TPB = 256;
    const int n2  = 2 * MROW;                    // 196,000
    const int nSB2 = (n2 + 1023) / 1024;         // 192

    // 1) histograms (+ merged W-fragment pack)
    count_kernel<<<NBLK + 6, TPB, 0, stream>>>(rows, cols, M, W1, W2, F1, F2);

    // 2) one scan chain
    block_sum_kernel<<<nSB2, 256, 0, stream>>>(M, partials, n2);
    scan_partials_kernel<<<1, 256, 0, stream>>>(partials, nSB2);
    scan_final_kernel<<<nSB2, 256, 0, stream>>>(M, partials, Ms, n2);

    // 3) LDS-sorted scatter
    scatter_kernel<<<NBLK, TPB, 0, stream>>>(rows, cols, ew, M, Ms, pkA, pkR);

    // 4) fill ∥ deg
    fill_deg_kernel<<<2 * NBKT, TPB, 0, stream>>>(pkA, pkR, Ms, csr, offsets, dis);

    // 5) h1 = dis * (x @ W1) via MFMA (over dead pkA)
    gemm1_mfma<<<(N_NODES + 63) / 64, TPB, 0, stream>>>(x, F1, dis, h1);

    // 6) t = dis*relu(dis*gather(h1) + b1)  (over dead pkR)
    gather1_kernel<<<N_NODES / 16, 512, 0, stream>>>(h1, csr, offsets, b1, dis, t);

    // 7) out = (dis*gather(t)) @ W2 + b2  — gather2 with fused MFMA epilogue
    gather2_gemm2_kernel<<<N_NODES / 16, 512, 0, stream>>>(t, csr, offsets, dis, F2, b2, out);
}

// Round 16
// 162.862 us; speedup vs baseline: 1.3765x; 1.0257x over previous
//
#include <hip/hip_runtime.h>
#include <hip/hip_fp16.h>

#define N_NODES 100000
#define N_EDGES 1600000
#define IN_DIM 128
#define HID_DIM 64
#define OUT_DIM 64
#define NBKT 196    // node buckets of 512: ceil(100000/512)
#define BSH 9       // bucket shift
#define BMSK 511
#define NBLK 500    // edge-chunk blocks
#define CHUNK 3200  // 500*3200 = 1,600,000
#define MROW (NBKT * NBLK)   // 98,000

typedef _Float16 half8 __attribute__((ext_vector_type(8)));
typedef float f32x4 __attribute__((ext_vector_type(4)));

// ============ count (+ merged wfrag): per-block histograms, int4 edge loads ============
__global__ void count_kernel(const int* __restrict__ rows, const int* __restrict__ cols,
                             int* __restrict__ M,
                             const float* __restrict__ W1, const float* __restrict__ W2,
                             __half* __restrict__ F1, __half* __restrict__ F2) {
    __shared__ unsigned hc[NBKT], hr[NBKT];
    if (blockIdx.x >= NBLK) {
        int t = (blockIdx.x - NBLK) * 256 + threadIdx.x;
        if (t < 1024) {
            int lane = t & 63, fg = t >> 6;
            int col = (fg & 3) * 16 + (lane & 15);
            int kb = (fg >> 2) * 32 + (lane >> 4) * 8;
            __half v[8];
#pragma unroll
            for (int j = 0; j < 8; ++j) v[j] = __float2half(W1[(kb + j) * 64 + col]);
            *reinterpret_cast<uint4*>(F1 + (size_t)t * 8) = *reinterpret_cast<uint4*>(v);
        } else if (t < 1536) {
            int u = t - 1024;
            int lane = u & 63, fg = u >> 6;
            int col = (fg & 3) * 16 + (lane & 15);
            int kb = (fg >> 2) * 32 + (lane >> 4) * 8;
            __half v[8];
#pragma unroll
            for (int j = 0; j < 8; ++j) v[j] = __float2half(W2[(kb + j) * 64 + col]);
            *reinterpret_cast<uint4*>(F2 + (size_t)u * 8) = *reinterpret_cast<uint4*>(v);
        }
        return;
    }
    for (int i = threadIdx.x; i < NBKT; i += 256) { hc[i] = 0; hr[i] = 0; }
    __syncthreads();
    const int4* r4 = (const int4*)(rows + blockIdx.x * CHUNK);
    const int4* c4 = (const int4*)(cols + blockIdx.x * CHUNK);
    for (int i = threadIdx.x; i < CHUNK / 4; i += 256) {
        int4 r = r4[i], c = c4[i];
        atomicAdd(&hr[r.x >> BSH], 1u); atomicAdd(&hr[r.y >> BSH], 1u);
        atomicAdd(&hr[r.z >> BSH], 1u); atomicAdd(&hr[r.w >> BSH], 1u);
        atomicAdd(&hc[c.x >> BSH], 1u); atomicAdd(&hc[c.y >> BSH], 1u);
        atomicAdd(&hc[c.z >> BSH], 1u); atomicAdd(&hc[c.w >> BSH], 1u);
    }
    __syncthreads();
    for (int i = threadIdx.x; i < NBKT; i += 256) {
        M[i * NBLK + blockIdx.x] = (int)hc[i];
        M[MROW + i * NBLK + blockIdx.x] = (int)hr[i];
    }
}

// ============ exclusive scan (2 kernels; partials scan folded into final) ============
__global__ void block_sum_kernel(const int* __restrict__ counts, int* __restrict__ partials, int n) {
    __shared__ int sh[256];
    int base = blockIdx.x * 1024;
    int s = 0;
    for (int i = threadIdx.x; i < 1024; i += 256) {
        int idx = base + i;
        s += (idx < n) ? counts[idx] : 0;
    }
    sh[threadIdx.x] = s;
    __syncthreads();
    for (int off = 128; off > 0; off >>= 1) {
        if (threadIdx.x < off) sh[threadIdx.x] += sh[threadIdx.x + off];
        __syncthreads();
    }
    if (threadIdx.x == 0) partials[blockIdx.x] = sh[0];
}

__global__ void scan_final_kernel(const int* __restrict__ counts, const int* __restrict__ partials,
                                  int* __restrict__ offsets, int n, int nb) {
    __shared__ int sh[256];
    __shared__ int pp[256];
    int t = threadIdx.x;
    // redundant per-block scan of partials (nb <= 256): integer, deterministic
    pp[t] = (t < nb) ? partials[t] : 0;
    __syncthreads();
    for (int off = 1; off < 256; off <<= 1) {
        int add = (t >= off) ? pp[t - off] : 0;
        __syncthreads();
        pp[t] += add;
        __syncthreads();
    }
    const int base0 = (blockIdx.x > 0) ? pp[blockIdx.x - 1] : 0;  // exclusive block base

    int idx0 = blockIdx.x * 1024 + t * 4;
    int v[4];
    int s = 0;
#pragma unroll
    for (int j = 0; j < 4; ++j) {
        int id = idx0 + j;
        v[j] = (id < n) ? counts[id] : 0;
        s += v[j];
    }
    sh[t] = s;
    __syncthreads();
    for (int off = 1; off < 256; off <<= 1) {
        int add = (t >= off) ? sh[t - off] : 0;
        __syncthreads();
        sh[t] += add;
        __syncthreads();
    }
    int run = sh[t] - s + base0;
#pragma unroll
    for (int j = 0; j < 4; ++j) {
        int id = idx0 + j;
        if (id < n) offsets[id] = run;
        run += v[j];
    }
    if (idx0 <= n - 1 && n - 1 < idx0 + 4) offsets[n] = run;
}

// ============ scatter: block-local LDS counting sort, coalesced write-out ============
__global__ __launch_bounds__(256) void scatter_kernel(
        const int* __restrict__ rows, const int* __restrict__ cols,
        const float* __restrict__ w, const int* __restrict__ M, const int* __restrict__ Ms,
        unsigned long long* __restrict__ pkA, unsigned* __restrict__ pkR) {
    __shared__ unsigned long long pay[CHUNK];
    __shared__ unsigned char bkt[CHUNK];
    __shared__ unsigned scn[256];
    __shared__ unsigned base[NBKT], cur[NBKT], gbase[NBKT];
    const int blk = blockIdx.x, t = threadIdx.x;
    const int s = blk * CHUNK;
    const int4* r4 = (const int4*)(rows + s);
    const int4* c4 = (const int4*)(cols + s);
    const float4* w4 = (const float4*)(w + s);

    unsigned cnt = (t < NBKT) ? (unsigned)M[t * NBLK + blk] : 0;
    scn[t] = cnt;
    __syncthreads();
    for (int off = 1; off < 256; off <<= 1) {
        unsigned a = (t >= off) ? scn[t - off] : 0;
        __syncthreads();
        scn[t] += a;
        __syncthreads();
    }
    if (t < NBKT) {
        unsigned b0 = scn[t] - cnt;
        base[t] = b0; cur[t] = b0;
        gbase[t] = (unsigned)Ms[t * NBLK + blk];
    }
    __syncthreads();
#define PUTA(RV, CV, WV) { unsigned b = (unsigned)(CV) >> BSH; \
        unsigned p = atomicAdd(&cur[b], 1u); \
        pay[p] = ((unsigned long long)__float_as_uint(WV) << 32) | \
                 (unsigned)((((CV) & BMSK) << 17) | (RV)); \
        bkt[p] = (unsigned char)b; }
    for (int i = t; i < CHUNK / 4; i += 256) {
        int4 rr = r4[i]; int4 cc = c4[i]; float4 ww = w4[i];
        PUTA(rr.x, cc.x, ww.x); PUTA(rr.y, cc.y, ww.y);
        PUTA(rr.z, cc.z, ww.z); PUTA(rr.w, cc.w, ww.w);
    }
    __syncthreads();
    for (int i = t; i < CHUNK; i += 256) {
        unsigned b = bkt[i];
        pkA[gbase[b] + (i - base[b])] = pay[i];
    }
    __syncthreads();

    cnt = (t < NBKT) ? (unsigned)M[MROW + t * NBLK + blk] : 0;
    scn[t] = cnt;
    __syncthreads();
    for (int off = 1; off < 256; off <<= 1) {
        unsigned a = (t >= off) ? scn[t - off] : 0;
        __syncthreads();
        scn[t] += a;
        __syncthreads();
    }
    if (t < NBKT) {
        unsigned b0 = scn[t] - cnt;
        base[t] = b0; cur[t] = b0;
        gbase[t] = (unsigned)Ms[MROW + t * NBLK + blk] - (unsigned)N_EDGES;
    }
    __syncthreads();
    unsigned* pay32 = (unsigned*)pay;
#define PUTR(RV, WV) { unsigned b = (unsigned)(RV) >> BSH; \
        unsigned p = atomicAdd(&cur[b], 1u); \
        pay32[p] = ((unsigned)__half_as_ushort(__float2half(WV)) << 16) | (unsigned)((RV) & BMSK); \
        bkt[p] = (unsigned char)b; }
    for (int i = t; i < CHUNK / 4; i += 256) {
        int4 rr = r4[i]; float4 ww = w4[i];
        PUTR(rr.x, ww.x); PUTR(rr.y, ww.y); PUTR(rr.z, ww.z); PUTR(rr.w, ww.w);
    }
    __syncthreads();
    for (int i = t; i < CHUNK; i += 256) {
        unsigned b = bkt[i];
        pkR[gbase[b] + (i - base[b])] = pay32[i];
    }
}

// ============ merged fill (col region) + deg reduce (row region) ============
__global__ __launch_bounds__(256) void fill_deg_kernel(
        const unsigned long long* __restrict__ pkA, const unsigned* __restrict__ pkR,
        const int* __restrict__ Ms, int2* __restrict__ csr,
        int* __restrict__ offsets, float* __restrict__ dis) {
    __shared__ unsigned sh[768];
    const int t = threadIdx.x;
    if (blockIdx.x < NBKT) {
        unsigned* hist = sh;
        unsigned* pairs = sh + 512;
        const int b = blockIdx.x;
        hist[t] = 0; hist[t + 256] = 0;
        __syncthreads();
        const int s = Ms[b * NBLK];
        const int e = Ms[(b + 1) * NBLK];
        for (int i = s + t; i < e; i += 256) {
            unsigned lo = (unsigned)pkA[i];
            atomicAdd(&hist[(lo >> 17) & (unsigned)BMSK], 1u);
        }
        __syncthreads();
        unsigned h0 = hist[2 * t], h1 = hist[2 * t + 1];
        pairs[t] = h0 + h1;
        __syncthreads();
        for (int off = 1; off < 256; off <<= 1) {
            unsigned add = (t >= off) ? pairs[t - off] : 0;
            __syncthreads();
            pairs[t] += add;
            __syncthreads();
        }
        unsigned P = pairs[t] - (h0 + h1) + (unsigned)s;
        unsigned e0 = P, e1 = P + h0;
        int n0 = b * 512 + 2 * t;
        int n1 = n0 + 1;
        if (n0 <= N_NODES) offsets[n0] = (int)e0;
        if (n1 <= N_NODES) offsets[n1] = (int)e1;
        hist[2 * t] = e0; hist[2 * t + 1] = e1;
        __syncthreads();
        for (int i = s + t; i < e; i += 256) {
            unsigned long long p = pkA[i];
            unsigned lo = (unsigned)p;
            unsigned cl = (lo >> 17) & (unsigned)BMSK;
            int r = (int)(lo & 0x1FFFFu);
            unsigned pos = atomicAdd(&hist[cl], 1u);
            csr[pos] = make_int2(r, (int)(unsigned)(p >> 32));
        }
    } else {
        float* acc = (float*)sh;
        const int b = blockIdx.x - NBKT;
        acc[t] = 0.f; acc[t + 256] = 0.f;
        __syncthreads();
        const int s = Ms[MROW + b * NBLK] - N_EDGES;
        const int e = Ms[MROW + (b + 1) * NBLK] - N_EDGES;
        for (int i = s + t; i < e; i += 256) {
            unsigned u = pkR[i];
            float wv = __half2float(__ushort_as_half((unsigned short)(u >> 16)));
            atomicAdd(&acc[u & (unsigned)BMSK], wv);
        }
        __syncthreads();
#pragma unroll
        for (int k = 0; k < 2; ++k) {
            int node = b * 512 + t + k * 256;
            if (node < N_NODES) {
                float d = acc[t + k * 256];
                dis[node] = d > 0.f ? rsqrtf(fmaxf(d, 1e-12f)) : 0.f;
            }
        }
    }
}

// ============ GEMM1 (MFMA): h1[r] = dis[r] * (x @ W1)[r], fp16 out ============
__global__ __launch_bounds__(256) void gemm1_mfma(
        const float* __restrict__ x, const __half* __restrict__ F1,
        const float* __restrict__ dis, __half* __restrict__ h1) {
    const int wid = threadIdx.x >> 6, lane = threadIdx.x & 63;
    const int row0 = blockIdx.x * 64 + wid * 16;
    int arow = min(row0 + (lane & 15), N_NODES - 1);
    const int kb0 = (lane >> 4) * 8;
    const float* ap = x + (size_t)arow * 128 + kb0;

    f32x4 acc[4] = {};
#pragma unroll
    for (int c = 0; c < 4; ++c) {
        float4 a0 = *reinterpret_cast<const float4*>(ap + c * 32);
        float4 a1 = *reinterpret_cast<const float4*>(ap + c * 32 + 4);
        half8 af;
        af[0] = (_Float16)a0.x; af[1] = (_Float16)a0.y; af[2] = (_Float16)a0.z; af[3] = (_Float16)a0.w;
        af[4] = (_Float16)a1.x; af[5] = (_Float16)a1.y; af[6] = (_Float16)a1.z; af[7] = (_Float16)a1.w;
#pragma unroll
        for (int ct = 0; ct < 4; ++ct) {
            half8 bf = *reinterpret_cast<const half8*>(F1 + ((size_t)(c * 4 + ct) * 64 + lane) * 8);
            acc[ct] = __builtin_amdgcn_mfma_f32_16x16x32_f16(af, bf, acc[ct], 0, 0, 0);
        }
    }
    const int prow = row0 + ((lane >> 4) << 2);
    const int col = lane & 15;
#pragma unroll
    for (int r = 0; r < 4; ++r) {
        int rr = prow + r;
        if (rr < N_NODES) {
            float dv = dis[rr];
#pragma unroll
            for (int ct = 0; ct < 4; ++ct)
                h1[(size_t)rr * 64 + ct * 16 + col] = __float2half(acc[ct][r] * dv);
        }
    }
}

// ============ GEMM2 (MFMA): out = g @ W2 + b2, fp32 out ============
__global__ __launch_bounds__(256) void gemm2_mfma(
        const __half* __restrict__ g, const __half* __restrict__ F2,
        const float* __restrict__ b2, float* __restrict__ out) {
    const int wid = threadIdx.x >> 6, lane = threadIdx.x & 63;
    const int row0 = blockIdx.x * 64 + wid * 16;
    int arow = min(row0 + (lane & 15), N_NODES - 1);
    const int kb0 = (lane >> 4) * 8;
    const __half* ap = g + (size_t)arow * 64 + kb0;

    f32x4 acc[4] = {};
#pragma unroll
    for (int c = 0; c < 2; ++c) {
        half8 af = *reinterpret_cast<const half8*>(ap + c * 32);
#pragma unroll
        for (int ct = 0; ct < 4; ++ct) {
            half8 bf = *reinterpret_cast<const half8*>(F2 + ((size_t)(c * 4 + ct) * 64 + lane) * 8);
            acc[ct] = __builtin_amdgcn_mfma_f32_16x16x32_f16(af, bf, acc[ct], 0, 0, 0);
        }
    }
    const int prow = row0 + ((lane >> 4) << 2);
    const int col = lane & 15;
#pragma unroll
    for (int ct = 0; ct < 4; ++ct) {
        float bb = b2[ct * 16 + col];
#pragma unroll
        for (int r = 0; r < 4; ++r) {
            int rr = prow + r;
            if (rr < N_NODES) out[(size_t)rr * 64 + ct * 16 + col] = acc[ct][r] + bb;
        }
    }
}

// ============ gather: TWO nodes per wave (R13 proven config) ============
__device__ __forceinline__ void fma8(float* a, uint4 u, float nv) {
    float2 f;
    f = __half22float2(__builtin_bit_cast(__half2, u.x)); a[0] = fmaf(f.x, nv, a[0]); a[1] = fmaf(f.y, nv, a[1]);
    f = __half22float2(__builtin_bit_cast(__half2, u.y)); a[2] = fmaf(f.x, nv, a[2]); a[3] = fmaf(f.y, nv, a[3]);
    f = __half22float2(__builtin_bit_cast(__half2, u.z)); a[4] = fmaf(f.x, nv, a[4]); a[5] = fmaf(f.y, nv, a[5]);
    f = __half22float2(__builtin_bit_cast(__half2, u.w)); a[6] = fmaf(f.x, nv, a[6]); a[7] = fmaf(f.y, nv, a[7]);
}

template <int BIAS_RELU>
__device__ __forceinline__ void gather_epilogue(float* a, int node, int q,
                                                const float* bias, const float* dis,
                                                __half* outh) {
    float dv = dis[node];
    if (BIAS_RELU) {
        const float4 b0 = *reinterpret_cast<const float4*>(bias + (q << 3));
        const float4 b1 = *reinterpret_cast<const float4*>(bias + (q << 3) + 4);
        a[0] = fmaxf(fmaf(a[0], dv, b0.x), 0.f) * dv; a[1] = fmaxf(fmaf(a[1], dv, b0.y), 0.f) * dv;
        a[2] = fmaxf(fmaf(a[2], dv, b0.z), 0.f) * dv; a[3] = fmaxf(fmaf(a[3], dv, b0.w), 0.f) * dv;
        a[4] = fmaxf(fmaf(a[4], dv, b1.x), 0.f) * dv; a[5] = fmaxf(fmaf(a[5], dv, b1.y), 0.f) * dv;
        a[6] = fmaxf(fmaf(a[6], dv, b1.z), 0.f) * dv; a[7] = fmaxf(fmaf(a[7], dv, b1.w), 0.f) * dv;
    } else {
#pragma unroll
        for (int k = 0; k < 8; ++k) a[k] *= dv;
    }
    __half2 o0 = __float22half2_rn(make_float2(a[0], a[1]));
    __half2 o1 = __float22half2_rn(make_float2(a[2], a[3]));
    __half2 o2 = __float22half2_rn(make_float2(a[4], a[5]));
    __half2 o3 = __float22half2_rn(make_float2(a[6], a[7]));
    uint4 u = make_uint4(__builtin_bit_cast(unsigned, o0), __builtin_bit_cast(unsigned, o1),
                         __builtin_bit_cast(unsigned, o2), __builtin_bit_cast(unsigned, o3));
    *reinterpret_cast<uint4*>(outh + ((size_t)node << 6) + (q << 3)) = u;
}

template <int BIAS_RELU>
__global__ __launch_bounds__(512) void gather_vec_kernel(
        const __half* __restrict__ h, const int2* __restrict__ csr,
        const int* __restrict__ offsets, const float* __restrict__ bias,
        const float* __restrict__ dis, __half* __restrict__ outh, int n) {
    const int wid = threadIdx.x >> 6;
    const int n0 = blockIdx.x * 16 + wid * 2;
    const int n1 = n0 + 1;
    const int lane = threadIdx.x & 63;
    const int q = lane & 7;
    const int g = lane >> 3;
    const int s0 = offsets[n0], e0 = offsets[n0 + 1];
    const int s1 = offsets[n1], e1 = offsets[n1 + 1];
    const int cl0 = max(e0 - 1, s0);
    const int cl1 = max(e1 - 1, s1);

    float xa[8] = {}, ya[8] = {};
    const int L = max(e0 - s0, e1 - s1);
    for (int j = 0; j < L; j += 16) {
        int iA0 = s0 + j + g,     iB0 = s0 + j + 8 + g;
        int iA1 = s1 + j + g,     iB1 = s1 + j + 8 + g;
        int2 pA0 = csr[min(iA0, cl0)];
        int2 pB0 = csr[min(iB0, cl0)];
        int2 pA1 = csr[min(iA1, cl1)];
        int2 pB1 = csr[min(iB1, cl1)];
        uint4 uA0 = *reinterpret_cast<const uint4*>(h + ((size_t)pA0.x << 6) + (q << 3));
        uint4 uB0 = *reinterpret_cast<const uint4*>(h + ((size_t)pB0.x << 6) + (q << 3));
        uint4 uA1 = *reinterpret_cast<const uint4*>(h + ((size_t)pA1.x << 6) + (q << 3));
        uint4 uB1 = *reinterpret_cast<const uint4*>(h + ((size_t)pB1.x << 6) + (q << 3));
        float nA0 = (iA0 < e0) ? __int_as_float(pA0.y) : 0.f;
        float nB0 = (iB0 < e0) ? __int_as_float(pB0.y) : 0.f;
        float nA1 = (iA1 < e1) ? __int_as_float(pA1.y) : 0.f;
        float nB1 = (iB1 < e1) ? __int_as_float(pB1.y) : 0.f;
        fma8(xa, uA0, nA0); fma8(xa, uB0, nB0);
        fma8(ya, uA1, nA1); fma8(ya, uB1, nB1);
    }
#pragma unroll
    for (int m = 8; m <= 32; m <<= 1) {
#pragma unroll
        for (int k = 0; k < 8; ++k) {
            xa[k] += __shfl_xor(xa[k], m);
            ya[k] += __shfl_xor(ya[k], m);
        }
    }
    if (g == 0) {
        gather_epilogue<BIAS_RELU>(xa, n0, q, bias, dis, outh);
    } else if (g == 1) {
        gather_epilogue<BIAS_RELU>(ya, n1, q, bias, dis, outh);
    }
}

extern "C" void kernel_launch(void* const* d_in, const int* in_sizes, int n_in,
                              void* d_out, int out_size, void* d_ws, size_t ws_size,
                              hipStream_t stream) {
    const float* x  = (const float*)d_in[0];
    const int*   ei = (const int*)d_in[1];
    const float* ew = (const float*)d_in[2];
    const float* W1 = (const float*)d_in[3];
    const float* b1 = (const float*)d_in[4];
    const float* W2 = (const float*)d_in[5];
    const float* b2 = (const float*)d_in[6];
    float* out = (float*)d_out;
    char*  ws  = (char*)d_ws;

    const int* rows = ei;
    const int* cols = ei + N_EDGES;

    // ---- workspace (byte offsets) ----
    int2*     csr      = (int2*)(ws + 0);                      // 12,800,000
    unsigned long long* pkA = (unsigned long long*)(ws + 12800000);  // [dies at fill]
    unsigned* pkR      = (unsigned*)(ws + 25600000);           // [dies at deg]
    __half*   h1       = (__half*)(ws + 12800000);             // fp16, over pkA
    __half*   g        = (__half*)(ws + 12800000);             // fp16, over h1 (gather2 out)
    __half*   t        = (__half*)(ws + 25600000);             // fp16, over pkR (gather1 out)
    int*      M        = (int*)(ws + 38400000);                // 784,000
    int*      Ms       = (int*)(ws + 39184000);                // 784,004
    int*      partials = (int*)(ws + 39968016);                // 768
    int*      offsets  = (int*)(ws + 39968784);                // 400,004
    float*    dis      = (float*)(ws + 40368800);              // 400,000
    __half*   F1       = (__half*)(ws + 40768800);             // 16,384
    __half*   F2       = (__half*)(ws + 40785184);             // 8,192

    const int TPB = 256;
    const int n2  = 2 * MROW;                    // 196,000
    const int nSB2 = (n2 + 1023) / 1024;         // 192

    // 1) histograms (+ merged W-fragment pack)
    count_kernel<<<NBLK + 6, TPB, 0, stream>>>(rows, cols, M, W1, W2, F1, F2);

    // 2) scan (block sums, then final with folded partials-scan)
    block_sum_kernel<<<nSB2, 256, 0, stream>>>(M, partials, n2);
    scan_final_kernel<<<nSB2, 256, 0, stream>>>(M, partials, Ms, n2, nSB2);

    // 3) LDS-sorted scatter into pkA (8B) + pkR (4B), coalesced writes
    scatter_kernel<<<NBLK, TPB, 0, stream>>>(rows, cols, ew, M, Ms, pkA, pkR);

    // 4) merged: offsets + CSR fill (col region) ∥ deg -> dis (row region)
    fill_deg_kernel<<<2 * NBKT, TPB, 0, stream>>>(pkA, pkR, Ms, csr, offsets, dis);

    // 5) h1 = dis * (x @ W1) via MFMA (over dead pkA)
    gemm1_mfma<<<(N_NODES + 63) / 64, TPB, 0, stream>>>(x, F1, dis, h1);

    // 6) t = dis*relu(dis*gather(h1) + b1)  (over dead pkR)
    gather_vec_kernel<1><<<N_NODES / 16, 512, 0, stream>>>(h1, csr, offsets, b1, dis, t, N_NODES);

    // 7) g = dis*gather(t)  (over dead h1)
    gather_vec_kernel<0><<<N_NODES / 16, 512, 0, stream>>>(t, csr, offsets, b1, dis, g, N_NODES);

    // 8) out = g @ W2 + b2 via MFMA
    gemm2_mfma<<<(N_NODES + 63) / 64, TPB, 0, stream>>>(g, F2, b2, out);
}